// Round 1
// baseline (227.684 us; speedup 1.0000x reference)
//
#include <hip/hip_runtime.h>
#include <math.h>

#define HH 256
#define WW 256
#define BB 8
#define NPB (HH*WW)          // pixels per batch image
#define NTOT (BB*HH*WW)      // total pixels
#define LARGE_F 1000000.0f

// ws layout (bytes):
// [0, NTOT*4)            : bufA  - g^2 for feat=(t==0) ("fg" EDT input), later overwritten with dA
// [NTOT*4, 2*NTOT*4)     : bufB  - g^2 for feat=(t==1) ("bg" EDT input), later overwritten with dB
// acc area at 2*NTOT*4:
//   uint maxA[8], uint maxB[8], int hasfg[8], then float lossacc[68]:
//     lossacc[0..4)   focal sums per pred
//     lossacc[4..36)  inter sums  [pred][b]
//     lossacc[36..68) union sums  [pred][b]  (sum of (p+t)*w; inter subtracted at the end)

__global__ void k_coldist(const int* __restrict__ tgt, float* __restrict__ bufA,
                          float* __restrict__ bufB, int* __restrict__ hasfg) {
    const int b = blockIdx.x;          // one block per batch image
    const int w = threadIdx.x;         // one thread per column
    const int base = b * NPB + w;

    // backward pass: nearest feature at h' >= h (matches flip/cummax/flip exactly,
    // including the (H-1-h)+LARGE value when no feature below)
    int nextA = -1, nextB = -1;
    #pragma unroll 8
    for (int h = HH - 1; h >= 0; --h) {
        int tv = tgt[base + h * WW];
        if (tv == 0) nextA = h; else nextB = h;
        float gA = (nextA >= 0) ? (float)(nextA - h) : ((float)(HH - 1 - h) + LARGE_F);
        float gB = (nextB >= 0) ? (float)(nextB - h) : ((float)(HH - 1 - h) + LARGE_F);
        bufA[base + h * WW] = gA;
        bufB[base + h * WW] = gB;
    }

    // forward pass: combine, clamp to LARGE, square
    int lastA = -1, lastB = -1;
    bool anyfg = false;
    #pragma unroll 8
    for (int h = 0; h < HH; ++h) {
        int tv = tgt[base + h * WW];
        if (tv == 0) lastA = h; else { lastB = h; anyfg = true; }
        float fA = (lastA >= 0) ? (float)(h - lastA) : ((float)h + LARGE_F);
        float fB = (lastB >= 0) ? (float)(h - lastB) : ((float)h + LARGE_F);
        float gA = fminf(fA, fminf(bufA[base + h * WW], LARGE_F));
        float gB = fminf(fB, fminf(bufB[base + h * WW], LARGE_F));
        gA = fminf(gA, LARGE_F);
        gB = fminf(gB, LARGE_F);
        bufA[base + h * WW] = gA * gA;
        bufB[base + h * WW] = gB * gB;
    }

    __shared__ int sf;
    if (threadIdx.x == 0) sf = 0;
    __syncthreads();
    if (anyfg) sf = 1;                 // benign race: all writers store 1
    __syncthreads();
    if (threadIdx.x == 0) hasfg[b] = sf;
}

__global__ void k_edt(float* __restrict__ bufA, float* __restrict__ bufB,
                      unsigned int* __restrict__ maxA, unsigned int* __restrict__ maxB) {
    const int r = blockIdx.x;          // row index: r = b*H + h
    const int b = r >> 8;
    const int t = threadIdx.x;         // output column
    __shared__ float sA[WW];
    __shared__ float sB[WW];
    sA[t] = bufA[r * WW + t];
    sB[t] = bufB[r * WW + t];
    __syncthreads();

    float dA = 3.4e38f, dB = 3.4e38f;
    #pragma unroll 8
    for (int j = 0; j < WW; ++j) {
        int dj = t - j;
        float c = (float)(dj * dj);
        dA = fminf(dA, sA[j] + c);
        dB = fminf(dB, sB[j] + c);
    }
    dA = sqrtf(dA);
    dB = sqrtf(dB);
    bufA[r * WW + t] = dA;             // in-place: row only depends on itself (LDS copy taken)
    bufB[r * WW + t] = dB;

    __shared__ unsigned int smA, smB;
    if (t == 0) { smA = 0u; smB = 0u; }
    __syncthreads();
    atomicMax(&smA, __float_as_uint(dA));   // nonneg floats: uint order == float order
    atomicMax(&smB, __float_as_uint(dB));
    __syncthreads();
    if (t == 0) { atomicMax(&maxA[b], smA); atomicMax(&maxB[b], smB); }
}

__device__ __forceinline__ float log_sigmoid(float x) {
    return fminf(x, 0.0f) - log1pf(expf(-fabsf(x)));
}

__global__ void k_loss(const float* __restrict__ p0, const float* __restrict__ p1,
                       const float* __restrict__ p2, const float* __restrict__ p3,
                       const int* __restrict__ tgt,
                       const float* __restrict__ bufA, const float* __restrict__ bufB,
                       const unsigned int* __restrict__ maxA, const unsigned int* __restrict__ maxB,
                       const int* __restrict__ hasfg,
                       float* __restrict__ acc) {
    const int idx = blockIdx.x * 256 + threadIdx.x;
    const int b = blockIdx.x >> 8;     // 256 blocks per batch, contiguous

    float mdA = __uint_as_float(maxA[b]);
    float mdB = __uint_as_float(maxB[b]);
    float md = fmaxf(mdA, mdB);
    bool valid = (hasfg[b] != 0) && (md > 0.0f);
    float inv = 3.0f / fmaxf(md, 1e-12f);

    int tv = tgt[idx];
    float tf = (float)tv;
    float absd = tv ? bufA[idx] : bufB[idx];
    float wgt = valid ? (1.0f + expf(-absd * inv)) : 1.0f;

    const float* preds[4] = {p0, p1, p2, p3};
    float vals[12];
    #pragma unroll
    for (int i = 0; i < 4; ++i) {
        float x = preds[i][idx];
        float p = 1.0f / (1.0f + expf(-x));
        float ce = -(tf * log_sigmoid(x) + (1.0f - tf) * log_sigmoid(-x));
        float p_t = p * tf + (1.0f - p) * (1.0f - tf);
        float om = 1.0f - p_t;
        float alpha_t = 0.25f * tf + 0.75f * (1.0f - tf);
        vals[i]     = alpha_t * om * om * ce;   // focal term
        vals[4 + i] = p * tf * wgt;             // inter term
        vals[8 + i] = (p + tf) * wgt;           // union term (pre-subtraction)
    }

    // block reduction: wave shuffle then cross-wave via LDS
    __shared__ float red[4][12];
    const int lane = threadIdx.x & 63;
    const int wv = threadIdx.x >> 6;
    #pragma unroll
    for (int q = 0; q < 12; ++q) {
        float v = vals[q];
        #pragma unroll
        for (int o = 32; o > 0; o >>= 1) v += __shfl_down(v, o, 64);
        if (lane == 0) red[wv][q] = v;
    }
    __syncthreads();
    if (threadIdx.x < 12) {
        int q = threadIdx.x;
        float s = red[0][q] + red[1][q] + red[2][q] + red[3][q];
        float* dst;
        if (q < 4)       dst = &acc[q];                    // focal[pred]
        else if (q < 8)  dst = &acc[4 + (q - 4) * 8 + b];  // inter[pred][b]
        else             dst = &acc[36 + (q - 8) * 8 + b]; // union[pred][b]
        atomicAdd(dst, s);
    }
}

__global__ void k_final(const float* __restrict__ acc, float* __restrict__ out) {
    if (threadIdx.x == 0 && blockIdx.x == 0) {
        const float coef[4] = {1.0f, 0.4f, 0.2f, 0.4f / 3.0f};
        float total = 0.0f;
        #pragma unroll
        for (int i = 0; i < 4; ++i) {
            float fm = acc[i] / (float)NTOT;
            float ious = 0.0f;
            #pragma unroll
            for (int b = 0; b < BB; ++b) {
                float in_ = acc[4 + i * 8 + b];
                float un  = acc[36 + i * 8 + b] - in_;
                ious += (in_ + 1e-6f) / (un + 1e-6f);
            }
            total += coef[i] * (fm + (1.0f - ious * 0.125f));
        }
        out[0] = total;
    }
}

extern "C" void kernel_launch(void* const* d_in, const int* in_sizes, int n_in,
                              void* d_out, int out_size, void* d_ws, size_t ws_size,
                              hipStream_t stream) {
    const float* p0 = (const float*)d_in[0];
    const float* p1 = (const float*)d_in[1];
    const float* p2 = (const float*)d_in[2];
    const float* p3 = (const float*)d_in[3];
    const int* tgt = (const int*)d_in[4];
    float* out = (float*)d_out;

    float* bufA = (float*)d_ws;
    float* bufB = bufA + NTOT;
    char* accbase = (char*)(bufB + NTOT);
    unsigned int* maxA = (unsigned int*)accbase;           // [8]
    unsigned int* maxB = maxA + 8;                         // [8]
    int* hasfg = (int*)(maxB + 8);                         // [8]
    float* lossacc = (float*)(hasfg + 8);                  // [68]

    // zero all accumulators: (8+8+8+68)*4 = 368 bytes
    hipMemsetAsync(accbase, 0, 368, stream);

    k_coldist<<<BB, WW, 0, stream>>>(tgt, bufA, bufB, hasfg);
    k_edt<<<BB * HH, WW, 0, stream>>>(bufA, bufB, maxA, maxB);
    k_loss<<<NTOT / 256, 256, 0, stream>>>(p0, p1, p2, p3, tgt, bufA, bufB,
                                           maxA, maxB, hasfg, lossacc);
    k_final<<<1, 64, 0, stream>>>(lossacc, out);
}

// Round 2
// 176.619 us; speedup vs baseline: 1.2891x; 1.2891x over previous
//
#include <hip/hip_runtime.h>
#include <math.h>

#define HH 256
#define WW 256
#define BB 8
#define NPB (HH*WW)
#define NTOT (BB*HH*WW)
#define LARGE_F 1000000.0f

// ws layout:
// [0, NTOT*4)                    : dsel  - selected |dist| per pixel (fg if t==1 else bg)
// [NTOT*4, NTOT*4 + 64KB)        : maskA - per-column 256-bit feature masks (bit = (t==0)),
//                                  layout mask[(b*4 + k)*256 + w], word k covers h in [64k,64k+64)
// then acc area:
//   uint maxA[8], uint maxB[8], int hasfg[8], float lossacc[68]
//     lossacc[0..4)   focal sums per pred
//     lossacc[4..36)  inter sums  [pred][b]
//     lossacc[36..68) union sums  [pred][b]

__global__ void k_mask(const int* __restrict__ tgt, unsigned long long* __restrict__ mask,
                       int* __restrict__ hasfg) {
    const int b = blockIdx.x >> 2;
    const int k = blockIdx.x & 3;
    const int w = threadIdx.x;
    const int base = b * NPB + k * 64 * WW + w;
    unsigned long long word = 0ull;
    #pragma unroll
    for (int i = 0; i < 64; ++i) {
        int tv = tgt[base + i * WW];
        word |= ((unsigned long long)(tv == 0)) << i;
    }
    mask[(b * 4 + k) * WW + w] = word;
    // any zero bit => some t==1 in this chunk
    if (__any(word != ~0ull)) {
        if ((threadIdx.x & 63) == 0) atomicOr(&hasfg[b], 1);
    }
}

// distance^2 along column at row h, given the column's 4 mask words (bit set = feature)
__device__ __forceinline__ float col_g2(unsigned long long m0, unsigned long long m1,
                                        unsigned long long m2, unsigned long long m3,
                                        int h, int k0, int rbit,
                                        unsigned long long maskle, unsigned long long maskge) {
    // words restricted for "last feature <= h"
    unsigned long long wL0 = (k0 > 0) ? m0 : (m0 & maskle);
    unsigned long long wL1 = (k0 > 1) ? m1 : ((k0 == 1) ? (m1 & maskle) : 0ull);
    unsigned long long wL2 = (k0 > 2) ? m2 : ((k0 == 2) ? (m2 & maskle) : 0ull);
    unsigned long long wL3 = (k0 == 3) ? (m3 & maskle) : 0ull;
    // words restricted for "next feature >= h"
    unsigned long long wN0 = (k0 == 0) ? (m0 & maskge) : 0ull;
    unsigned long long wN1 = (k0 < 1) ? m1 : ((k0 == 1) ? (m1 & maskge) : 0ull);
    unsigned long long wN2 = (k0 < 2) ? m2 : ((k0 == 2) ? (m2 & maskge) : 0ull);
    unsigned long long wN3 = (k0 < 3) ? m3 : (m3 & maskge);

    int L = -1;
    L = wL0 ? (63  - __builtin_clzll(wL0)) : L;
    L = wL1 ? (127 - __builtin_clzll(wL1)) : L;
    L = wL2 ? (191 - __builtin_clzll(wL2)) : L;
    L = wL3 ? (255 - __builtin_clzll(wL3)) : L;

    int N = 1 << 30;
    N = wN3 ? (192 + __builtin_ctzll(wN3)) : N;
    N = wN2 ? (128 + __builtin_ctzll(wN2)) : N;
    N = wN1 ? (64  + __builtin_ctzll(wN1)) : N;
    N = wN0 ? (__builtin_ctzll(wN0))       : N;

    float f  = (L >= 0)  ? (float)(h - L) : ((float)h + LARGE_F);
    float bk = (N < HH)  ? (float)(N - h) : ((float)(HH - 1 - h) + LARGE_F);
    float g  = fminf(fminf(f, bk), LARGE_F);
    return g * g;
}

__global__ void k_edt2(const unsigned long long* __restrict__ mask,
                       float* __restrict__ dsel,
                       unsigned int* __restrict__ maxA, unsigned int* __restrict__ maxB) {
    const int b   = blockIdx.x >> 6;
    const int grp = blockIdx.x & 63;
    const int wv   = threadIdx.x >> 6;
    const int lane = threadIdx.x & 63;
    const int h = grp * 4 + wv;          // this wave's row
    const int r = b * HH + h;            // global row

    // lane's 4 columns: c_q = lane + 64q ; load their mask words into registers
    unsigned long long m[4][4];
    #pragma unroll
    for (int q = 0; q < 4; ++q) {
        #pragma unroll
        for (int k = 0; k < 4; ++k)
            m[q][k] = mask[(b * 4 + k) * WW + lane + 64 * q];
    }

    const int k0 = h >> 6;
    const int rbit = h & 63;
    const unsigned long long maskle = (rbit == 63) ? ~0ull : ((1ull << (rbit + 1)) - 1ull);
    const unsigned long long maskge = (~0ull) << rbit;

    __shared__ float2 rowbuf[4][WW];
    #pragma unroll
    for (int q = 0; q < 4; ++q) {
        float g2A = col_g2(m[q][0], m[q][1], m[q][2], m[q][3], h, k0, rbit, maskle, maskge);
        float g2B = col_g2(~m[q][0], ~m[q][1], ~m[q][2], ~m[q][3], h, k0, rbit, maskle, maskge);
        rowbuf[wv][lane + 64 * q] = make_float2(g2A, g2B);
    }
    __syncthreads();

    float dA0 = 3.4e38f, dA1 = 3.4e38f, dA2 = 3.4e38f, dA3 = 3.4e38f;
    float dB0 = 3.4e38f, dB1 = 3.4e38f, dB2 = 3.4e38f, dB3 = 3.4e38f;
    float f0 = (float)lane, f1 = (float)(lane + 64), f2 = (float)(lane + 128), f3 = (float)(lane + 192);
    #pragma unroll 8
    for (int j = 0; j < WW; ++j) {
        float2 gg = rowbuf[wv][j];
        dA0 = fminf(dA0, __builtin_fmaf(f0, f0, gg.x));
        dB0 = fminf(dB0, __builtin_fmaf(f0, f0, gg.y));
        dA1 = fminf(dA1, __builtin_fmaf(f1, f1, gg.x));
        dB1 = fminf(dB1, __builtin_fmaf(f1, f1, gg.y));
        dA2 = fminf(dA2, __builtin_fmaf(f2, f2, gg.x));
        dB2 = fminf(dB2, __builtin_fmaf(f2, f2, gg.y));
        dA3 = fminf(dA3, __builtin_fmaf(f3, f3, gg.x));
        dB3 = fminf(dB3, __builtin_fmaf(f3, f3, gg.y));
        f0 -= 1.0f; f1 -= 1.0f; f2 -= 1.0f; f3 -= 1.0f;
    }
    dA0 = sqrtf(dA0); dA1 = sqrtf(dA1); dA2 = sqrtf(dA2); dA3 = sqrtf(dA3);
    dB0 = sqrtf(dB0); dB1 = sqrtf(dB1); dB2 = sqrtf(dB2); dB3 = sqrtf(dB3);

    // t at (h, c_q): mask bit set => t==0 => use bg dist (dB); else fg dist (dA)
    float s0 = ((m[0][k0] >> rbit) & 1ull) ? dB0 : dA0;
    float s1 = ((m[1][k0] >> rbit) & 1ull) ? dB1 : dA1;
    float s2 = ((m[2][k0] >> rbit) & 1ull) ? dB2 : dA2;
    float s3 = ((m[3][k0] >> rbit) & 1ull) ? dB3 : dA3;
    dsel[r * WW + lane]       = s0;
    dsel[r * WW + lane + 64]  = s1;
    dsel[r * WW + lane + 128] = s2;
    dsel[r * WW + lane + 192] = s3;

    float wmA = fmaxf(fmaxf(dA0, dA1), fmaxf(dA2, dA3));
    float wmB = fmaxf(fmaxf(dB0, dB1), fmaxf(dB2, dB3));
    #pragma unroll
    for (int o = 32; o > 0; o >>= 1) {
        wmA = fmaxf(wmA, __shfl_down(wmA, o, 64));
        wmB = fmaxf(wmB, __shfl_down(wmB, o, 64));
    }
    if (lane == 0) {
        atomicMax(&maxA[b], __float_as_uint(wmA));
        atomicMax(&maxB[b], __float_as_uint(wmB));
    }
}

__device__ __forceinline__ float log_sigmoid(float x) {
    return fminf(x, 0.0f) - log1pf(expf(-fabsf(x)));
}

__global__ void k_loss(const float* __restrict__ p0, const float* __restrict__ p1,
                       const float* __restrict__ p2, const float* __restrict__ p3,
                       const int* __restrict__ tgt,
                       const float* __restrict__ dsel,
                       const unsigned int* __restrict__ maxA, const unsigned int* __restrict__ maxB,
                       const int* __restrict__ hasfg,
                       float* __restrict__ acc) {
    const int idx = blockIdx.x * 256 + threadIdx.x;
    const int b = blockIdx.x >> 8;

    float mdA = __uint_as_float(maxA[b]);
    float mdB = __uint_as_float(maxB[b]);
    float md = fmaxf(mdA, mdB);
    bool valid = (hasfg[b] != 0) && (md > 0.0f);
    float inv = 3.0f / fmaxf(md, 1e-12f);

    int tv = tgt[idx];
    float tf = (float)tv;
    float absd = dsel[idx];
    float wgt = valid ? (1.0f + expf(-absd * inv)) : 1.0f;

    const float* preds[4] = {p0, p1, p2, p3};
    float vals[12];
    #pragma unroll
    for (int i = 0; i < 4; ++i) {
        float x = preds[i][idx];
        float p = 1.0f / (1.0f + expf(-x));
        float ce = -(tf * log_sigmoid(x) + (1.0f - tf) * log_sigmoid(-x));
        float p_t = p * tf + (1.0f - p) * (1.0f - tf);
        float om = 1.0f - p_t;
        float alpha_t = 0.25f * tf + 0.75f * (1.0f - tf);
        vals[i]     = alpha_t * om * om * ce;
        vals[4 + i] = p * tf * wgt;
        vals[8 + i] = (p + tf) * wgt;
    }

    __shared__ float red[4][12];
    const int lane = threadIdx.x & 63;
    const int wv = threadIdx.x >> 6;
    #pragma unroll
    for (int q = 0; q < 12; ++q) {
        float v = vals[q];
        #pragma unroll
        for (int o = 32; o > 0; o >>= 1) v += __shfl_down(v, o, 64);
        if (lane == 0) red[wv][q] = v;
    }
    __syncthreads();
    if (threadIdx.x < 12) {
        int q = threadIdx.x;
        float s = red[0][q] + red[1][q] + red[2][q] + red[3][q];
        float* dst;
        if (q < 4)       dst = &acc[q];
        else if (q < 8)  dst = &acc[4 + (q - 4) * 8 + b];
        else             dst = &acc[36 + (q - 8) * 8 + b];
        atomicAdd(dst, s);
    }
}

__global__ void k_final(const float* __restrict__ acc, float* __restrict__ out) {
    if (threadIdx.x == 0 && blockIdx.x == 0) {
        const float coef[4] = {1.0f, 0.4f, 0.2f, 0.4f / 3.0f};
        float total = 0.0f;
        #pragma unroll
        for (int i = 0; i < 4; ++i) {
            float fm = acc[i] / (float)NTOT;
            float ious = 0.0f;
            #pragma unroll
            for (int b = 0; b < BB; ++b) {
                float in_ = acc[4 + i * 8 + b];
                float un  = acc[36 + i * 8 + b] - in_;
                ious += (in_ + 1e-6f) / (un + 1e-6f);
            }
            total += coef[i] * (fm + (1.0f - ious * 0.125f));
        }
        out[0] = total;
    }
}

extern "C" void kernel_launch(void* const* d_in, const int* in_sizes, int n_in,
                              void* d_out, int out_size, void* d_ws, size_t ws_size,
                              hipStream_t stream) {
    const float* p0 = (const float*)d_in[0];
    const float* p1 = (const float*)d_in[1];
    const float* p2 = (const float*)d_in[2];
    const float* p3 = (const float*)d_in[3];
    const int* tgt = (const int*)d_in[4];
    float* out = (float*)d_out;

    float* dsel = (float*)d_ws;
    unsigned long long* mask = (unsigned long long*)(dsel + NTOT);   // 8192 words
    char* accbase = (char*)(mask + BB * 4 * WW);
    unsigned int* maxA = (unsigned int*)accbase;    // [8]
    unsigned int* maxB = maxA + 8;                  // [8]
    int* hasfg = (int*)(maxB + 8);                  // [8]
    float* lossacc = (float*)(hasfg + 8);           // [68]

    hipMemsetAsync(accbase, 0, 368, stream);

    k_mask<<<BB * 4, WW, 0, stream>>>(tgt, mask, hasfg);
    k_edt2<<<BB * 64, 256, 0, stream>>>(mask, dsel, maxA, maxB);
    k_loss<<<NTOT / 256, 256, 0, stream>>>(p0, p1, p2, p3, tgt, dsel,
                                           maxA, maxB, hasfg, lossacc);
    k_final<<<1, 64, 0, stream>>>(lossacc, out);
}

// Round 3
// 144.874 us; speedup vs baseline: 1.5716x; 1.2191x over previous
//
#include <hip/hip_runtime.h>
#include <math.h>

#define HH 256
#define WW 256
#define BB 8
#define NPB (HH*WW)
#define NTOT (BB*HH*WW)
#define LARGE_F 1000000.0f

// ws layout (words, after dsel):
// [0, NTOT)        : dsel (float)  - SIGNED dist per pixel: t==1 -> +dA, t==0 -> -dB
// [NTOT, +8192)    : mask (u64[4096]) per-column 256-bit masks, bit=(t==0),
//                    mask[(b*4+k)*256 + w], word k covers rows [64k, 64k+64)
// acc area (words): 0:maxA[8] 8:maxB[8] 16:lossacc[68] 84:counter 85:hasfg4[32]
//   lossacc[0..4) focal | [4..36) inter[pred][b] | [36..68) union[pred][b]

__global__ void k_mask(const int* __restrict__ tgt, unsigned long long* __restrict__ mask,
                       unsigned int* __restrict__ acc) {
    const int b = blockIdx.x >> 2;
    const int k = blockIdx.x & 3;
    const int w = threadIdx.x;
    const int base = b * NPB + k * 64 * WW + w;
    unsigned long long word = 0ull;
    #pragma unroll
    for (int i = 0; i < 64; ++i) {
        int tv = tgt[base + i * WW];
        word |= ((unsigned long long)(tv == 0)) << i;
    }
    mask[(b * 4 + k) * WW + w] = word;

    // zero accumulators (block 0 only; all consumers are in later kernels)
    if (blockIdx.x == 0 && threadIdx.x < 85) acc[threadIdx.x] = 0u;

    // hasfg chunk flag: any t==1 (zero bit) in this 64-row chunk
    __shared__ int sf;
    if (threadIdx.x == 0) sf = 0;
    __syncthreads();
    if (word != ~0ull) sf = 1;          // benign race
    __syncthreads();
    if (threadIdx.x == 0) acc[85 + blockIdx.x] = (unsigned int)sf;
}

// squared column distance at row h given the column's 4 mask words (bit set = feature)
__device__ __forceinline__ float col_g2(unsigned long long m0, unsigned long long m1,
                                        unsigned long long m2, unsigned long long m3,
                                        int h, int k0,
                                        unsigned long long maskle, unsigned long long maskge) {
    unsigned long long wL0 = (k0 > 0) ? m0 : (m0 & maskle);
    unsigned long long wL1 = (k0 > 1) ? m1 : ((k0 == 1) ? (m1 & maskle) : 0ull);
    unsigned long long wL2 = (k0 > 2) ? m2 : ((k0 == 2) ? (m2 & maskle) : 0ull);
    unsigned long long wL3 = (k0 == 3) ? (m3 & maskle) : 0ull;
    unsigned long long wN0 = (k0 == 0) ? (m0 & maskge) : 0ull;
    unsigned long long wN1 = (k0 < 1) ? m1 : ((k0 == 1) ? (m1 & maskge) : 0ull);
    unsigned long long wN2 = (k0 < 2) ? m2 : ((k0 == 2) ? (m2 & maskge) : 0ull);
    unsigned long long wN3 = (k0 < 3) ? m3 : (m3 & maskge);

    int L = -1;
    L = wL0 ? (63  - __builtin_clzll(wL0)) : L;
    L = wL1 ? (127 - __builtin_clzll(wL1)) : L;
    L = wL2 ? (191 - __builtin_clzll(wL2)) : L;
    L = wL3 ? (255 - __builtin_clzll(wL3)) : L;

    int N = 1 << 30;
    N = wN3 ? (192 + __builtin_ctzll(wN3)) : N;
    N = wN2 ? (128 + __builtin_ctzll(wN2)) : N;
    N = wN1 ? (64  + __builtin_ctzll(wN1)) : N;
    N = wN0 ? (__builtin_ctzll(wN0))       : N;

    float f  = (L >= 0)  ? (float)(h - L) : ((float)h + LARGE_F);
    float bk = (N < HH)  ? (float)(N - h) : ((float)(HH - 1 - h) + LARGE_F);
    float g  = fminf(fminf(f, bk), LARGE_F);
    return g * g;
}

__device__ __forceinline__ float readlane_f(float v, int l) {
    return __uint_as_float(__builtin_amdgcn_readlane(__float_as_uint(v), (unsigned)l));
}

// one WAVE per row; lane holds g^2 for cols lane+64q in registers; candidates
// broadcast via v_readlane (scalar pipe) -- no LDS, no __syncthreads in hot loop.
__global__ void __launch_bounds__(256) k_edt3(const unsigned long long* __restrict__ mask,
                       float* __restrict__ dsel, unsigned int* __restrict__ acc) {
    const int b    = blockIdx.x >> 6;
    const int grp  = blockIdx.x & 63;
    const int wv   = threadIdx.x >> 6;
    const int lane = threadIdx.x & 63;
    const int h    = grp * 4 + wv;
    const int r    = b * HH + h;

    const int k0   = h >> 6;
    const int rbit = h & 63;
    const unsigned long long maskle = (rbit == 63) ? ~0ull : ((1ull << (rbit + 1)) - 1ull);
    const unsigned long long maskge = (~0ull) << rbit;

    float g2A[4], g2B[4];
    int msel[4];
    #pragma unroll
    for (int q = 0; q < 4; ++q) {
        unsigned long long m0 = mask[(b * 4 + 0) * WW + lane + 64 * q];
        unsigned long long m1 = mask[(b * 4 + 1) * WW + lane + 64 * q];
        unsigned long long m2 = mask[(b * 4 + 2) * WW + lane + 64 * q];
        unsigned long long m3 = mask[(b * 4 + 3) * WW + lane + 64 * q];
        g2A[q] = col_g2(m0, m1, m2, m3, h, k0, maskle, maskge);
        g2B[q] = col_g2(~m0, ~m1, ~m2, ~m3, h, k0, maskle, maskge);
        unsigned long long mk = (k0 == 0) ? m0 : (k0 == 1) ? m1 : (k0 == 2) ? m2 : m3;
        msel[q] = (int)((mk >> rbit) & 1ull);
    }

    float dA[4] = {3.4e38f, 3.4e38f, 3.4e38f, 3.4e38f};
    float dB[4] = {3.4e38f, 3.4e38f, 3.4e38f, 3.4e38f};

    #pragma unroll
    for (int cq = 0; cq < 4; ++cq) {
        // f_q = (lane + 64q) - (cq*64 + i), maintained by decrement
        float f0 = (float)(lane + 64 * 0 - cq * 64);
        float f1 = (float)(lane + 64 * 1 - cq * 64);
        float f2 = (float)(lane + 64 * 2 - cq * 64);
        float f3 = (float)(lane + 64 * 3 - cq * 64);
        #pragma unroll 8
        for (int i = 0; i < 64; ++i) {
            float gA = readlane_f(g2A[cq], i);
            float gB = readlane_f(g2B[cq], i);
            dA[0] = fminf(dA[0], __builtin_fmaf(f0, f0, gA));
            dB[0] = fminf(dB[0], __builtin_fmaf(f0, f0, gB));
            dA[1] = fminf(dA[1], __builtin_fmaf(f1, f1, gA));
            dB[1] = fminf(dB[1], __builtin_fmaf(f1, f1, gB));
            dA[2] = fminf(dA[2], __builtin_fmaf(f2, f2, gA));
            dB[2] = fminf(dB[2], __builtin_fmaf(f2, f2, gB));
            dA[3] = fminf(dA[3], __builtin_fmaf(f3, f3, gA));
            dB[3] = fminf(dB[3], __builtin_fmaf(f3, f3, gB));
            f0 -= 1.0f; f1 -= 1.0f; f2 -= 1.0f; f3 -= 1.0f;
        }
    }

    float wmA = -1.0f, wmB = -1.0f;
    #pragma unroll
    for (int q = 0; q < 4; ++q) {
        float a = sqrtf(dA[q]);
        float bq = sqrtf(dB[q]);
        wmA = fmaxf(wmA, a);
        wmB = fmaxf(wmB, bq);
        // mask bit set => t==0 => dist = -bg ; else t==1 => dist = +fg
        dsel[r * WW + lane + 64 * q] = msel[q] ? -bq : a;
    }
    #pragma unroll
    for (int o = 32; o > 0; o >>= 1) {
        wmA = fmaxf(wmA, __shfl_down(wmA, o, 64));
        wmB = fmaxf(wmB, __shfl_down(wmB, o, 64));
    }
    if (lane == 0) {
        atomicMax(&acc[0 + b], __float_as_uint(wmA));
        atomicMax(&acc[8 + b], __float_as_uint(wmB));
    }
}

__device__ __forceinline__ float log_sigmoid_fast(float x) {
    return fminf(x, 0.0f) - __logf(1.0f + __expf(-fabsf(x)));
}

__global__ void k_loss(const float* __restrict__ p0, const float* __restrict__ p1,
                       const float* __restrict__ p2, const float* __restrict__ p3,
                       const float* __restrict__ dsel,
                       unsigned int* __restrict__ acc_u,
                       float* __restrict__ out) {
    float* acc = (float*)acc_u;
    const int tix = blockIdx.x * 256 + threadIdx.x;   // 4-pixel group index
    const int idx = tix * 4;
    const int b = blockIdx.x >> 6;                    // 64 blocks per batch image

    float mdA = __uint_as_float(acc_u[0 + b]);
    float mdB = __uint_as_float(acc_u[8 + b]);
    float md = fmaxf(mdA, mdB);
    unsigned int hf = acc_u[85 + 4 * b] | acc_u[85 + 4 * b + 1] |
                      acc_u[85 + 4 * b + 2] | acc_u[85 + 4 * b + 3];
    bool valid = (hf != 0u) && (md > 0.0f);
    float inv = 3.0f / fmaxf(md, 1e-12f);

    float4 sd4 = *(const float4*)(dsel + idx);
    float4 x4[4];
    x4[0] = *(const float4*)(p0 + idx);
    x4[1] = *(const float4*)(p1 + idx);
    x4[2] = *(const float4*)(p2 + idx);
    x4[3] = *(const float4*)(p3 + idx);

    float vals[12];
    #pragma unroll
    for (int q = 0; q < 12; ++q) vals[q] = 0.0f;

    const float sds[4] = {sd4.x, sd4.y, sd4.z, sd4.w};
    #pragma unroll
    for (int px = 0; px < 4; ++px) {
        float sd = sds[px];
        float tf = (sd > 0.0f) ? 1.0f : 0.0f;
        float absd = fabsf(sd);
        float wgt = valid ? (1.0f + __expf(-absd * inv)) : 1.0f;
        #pragma unroll
        for (int i = 0; i < 4; ++i) {
            float x = (px == 0) ? ((i == 0) ? x4[0].x : (i == 1) ? x4[1].x : (i == 2) ? x4[2].x : x4[3].x)
                    : (px == 1) ? ((i == 0) ? x4[0].y : (i == 1) ? x4[1].y : (i == 2) ? x4[2].y : x4[3].y)
                    : (px == 2) ? ((i == 0) ? x4[0].z : (i == 1) ? x4[1].z : (i == 2) ? x4[2].z : x4[3].z)
                                : ((i == 0) ? x4[0].w : (i == 1) ? x4[1].w : (i == 2) ? x4[2].w : x4[3].w);
            float e = __expf(-x);
            float p = __builtin_amdgcn_rcpf(1.0f + e);
            float ce = -(tf * log_sigmoid_fast(x) + (1.0f - tf) * log_sigmoid_fast(-x));
            float p_t = p * tf + (1.0f - p) * (1.0f - tf);
            float om = 1.0f - p_t;
            float alpha_t = 0.25f * tf + 0.75f * (1.0f - tf);
            vals[i]     += alpha_t * om * om * ce;
            vals[4 + i] += p * tf * wgt;
            vals[8 + i] += (p + tf) * wgt;
        }
    }

    __shared__ float red[4][12];
    const int lane = threadIdx.x & 63;
    const int wv = threadIdx.x >> 6;
    #pragma unroll
    for (int q = 0; q < 12; ++q) {
        float v = vals[q];
        #pragma unroll
        for (int o = 32; o > 0; o >>= 1) v += __shfl_down(v, o, 64);
        if (lane == 0) red[wv][q] = v;
    }
    __syncthreads();
    if (threadIdx.x < 12) {
        int q = threadIdx.x;
        float s = red[0][q] + red[1][q] + red[2][q] + red[3][q];
        float* dst;
        if (q < 4)       dst = &acc[16 + q];
        else if (q < 8)  dst = &acc[16 + 4 + (q - 4) * 8 + b];
        else             dst = &acc[16 + 36 + (q - 8) * 8 + b];
        atomicAdd(dst, s);
    }
    __syncthreads();

    // last-block finalization
    __shared__ int is_last;
    if (threadIdx.x == 0) {
        __threadfence();
        unsigned int t = atomicAdd(&acc_u[84], 1u);
        is_last = (t == gridDim.x - 1) ? 1 : 0;
    }
    __syncthreads();
    if (is_last) {
        __shared__ float fin[68];
        if (threadIdx.x < 68) fin[threadIdx.x] = atomicAdd(&acc[16 + threadIdx.x], 0.0f);
        __syncthreads();
        if (threadIdx.x == 0) {
            const float coef[4] = {1.0f, 0.4f, 0.2f, 0.4f / 3.0f};
            float total = 0.0f;
            #pragma unroll
            for (int i = 0; i < 4; ++i) {
                float fm = fin[i] / (float)NTOT;
                float ious = 0.0f;
                #pragma unroll
                for (int bb = 0; bb < BB; ++bb) {
                    float in_ = fin[4 + i * 8 + bb];
                    float un  = fin[36 + i * 8 + bb] - in_;
                    ious += (in_ + 1e-6f) / (un + 1e-6f);
                }
                total += coef[i] * (fm + (1.0f - ious * 0.125f));
            }
            out[0] = total;
        }
    }
}

extern "C" void kernel_launch(void* const* d_in, const int* in_sizes, int n_in,
                              void* d_out, int out_size, void* d_ws, size_t ws_size,
                              hipStream_t stream) {
    const float* p0 = (const float*)d_in[0];
    const float* p1 = (const float*)d_in[1];
    const float* p2 = (const float*)d_in[2];
    const float* p3 = (const float*)d_in[3];
    const int* tgt = (const int*)d_in[4];
    float* out = (float*)d_out;

    float* dsel = (float*)d_ws;
    unsigned long long* mask = (unsigned long long*)(dsel + NTOT);   // 4096 words
    unsigned int* acc = (unsigned int*)(mask + BB * 4 * WW);         // 117 words

    k_mask<<<BB * 4, WW, 0, stream>>>(tgt, mask, acc);
    k_edt3<<<BB * 64, 256, 0, stream>>>(mask, dsel, acc);
    k_loss<<<NTOT / 1024, 256, 0, stream>>>(p0, p1, p2, p3, dsel, acc, out);
}